// Round 1
// baseline (103.652 us; speedup 1.0000x reference)
//
#include <hip/hip_runtime.h>

#define N_ROWS 600000
#define D_FEAT 128
#define N_SEG 50000

// One wave (64 lanes) per segment. Lane t owns columns [2t, 2t+1] as a float2.
// Sorted index -> binary search gives each segment's contiguous row range.
// Every output element is written exactly once (empty segments write 0),
// so no zero-init pass and no atomics are needed.
__global__ __launch_bounds__(64) void SegmentSum_20272245637565_kernel(
    const float* __restrict__ x,
    const int* __restrict__ idx,
    float* __restrict__ out) {

    const int seg = blockIdx.x;

    // lower_bound(idx, seg): first i with idx[i] >= seg
    int lo = 0, hi = N_ROWS;
    while (lo < hi) {
        int mid = (lo + hi) >> 1;
        if (idx[mid] < seg) lo = mid + 1; else hi = mid;
    }
    const int start = lo;

    // lower_bound(idx, seg + 1)
    hi = N_ROWS;
    while (lo < hi) {
        int mid = (lo + hi) >> 1;
        if (idx[mid] < seg + 1) lo = mid + 1; else hi = mid;
    }
    const int end = lo;

    const int t = threadIdx.x;  // 0..63
    const float2* __restrict__ x2 = reinterpret_cast<const float2*>(x);

    float2 acc = make_float2(0.0f, 0.0f);
    for (int r = start; r < end; ++r) {
        float2 v = x2[(long)r * (D_FEAT / 2) + t];
        acc.x += v.x;
        acc.y += v.y;
    }

    reinterpret_cast<float2*>(out)[(long)seg * (D_FEAT / 2) + t] = acc;
}

extern "C" void kernel_launch(void* const* d_in, const int* in_sizes, int n_in,
                              void* d_out, int out_size, void* d_ws, size_t ws_size,
                              hipStream_t stream) {
    const float* x  = (const float*)d_in[0];
    const int* idx  = (const int*)d_in[1];
    float* out      = (float*)d_out;

    SegmentSum_20272245637565_kernel<<<N_SEG, 64, 0, stream>>>(x, idx, out);
}

// Round 2
// 68.742 us; speedup vs baseline: 1.5079x; 1.5079x over previous
//
#include <hip/hip_runtime.h>

#define N_ROWS 600000
#define D_FEAT 128
#define N_SEG 50000

// Pass 1: offsets[s] = first row r with idx[r] >= s, for s in [0, N_SEG].
// Sorted index -> each row r where the index changes writes the boundary for
// every segment id in (idx[r-1], idx[r]]. Covers all of [0, N_SEG] exactly once.
__global__ __launch_bounds__(256) void seg_offsets_kernel(
    const int* __restrict__ idx, int* __restrict__ offsets) {
    int r = blockIdx.x * 256 + threadIdx.x;
    if (r >= N_ROWS) return;
    int cur = idx[r];
    int prev = (r == 0) ? -1 : idx[r - 1];
    for (int s = prev + 1; s <= cur; ++s) offsets[s] = r;
    if (r == N_ROWS - 1)
        for (int s = cur + 1; s <= N_SEG; ++s) offsets[s] = N_ROWS;
}

// Pass 2: one wave per segment, 4 segments (4 waves) per 256-thread block.
// Lane t owns columns [2t, 2t+1] (float2, 512 B/row coalesced per wave).
// Row loop unrolled x4 with independent accumulators -> 4 loads in flight.
__global__ __launch_bounds__(256) void SegmentSum_20272245637565_kernel(
    const float* __restrict__ x, const int* __restrict__ offsets,
    float* __restrict__ out) {
    const int wave = threadIdx.x >> 6;          // 0..3
    const int lane = threadIdx.x & 63;
    const int seg  = blockIdx.x * 4 + wave;

    const int start = offsets[seg];
    const int end   = offsets[seg + 1];

    const float2* __restrict__ x2 = reinterpret_cast<const float2*>(x);

    float2 a0{0.f, 0.f}, a1{0.f, 0.f}, a2{0.f, 0.f}, a3{0.f, 0.f};
    int r = start;
    for (; r + 4 <= end; r += 4) {
        float2 v0 = x2[(long)(r + 0) * 64 + lane];
        float2 v1 = x2[(long)(r + 1) * 64 + lane];
        float2 v2 = x2[(long)(r + 2) * 64 + lane];
        float2 v3 = x2[(long)(r + 3) * 64 + lane];
        a0.x += v0.x; a0.y += v0.y;
        a1.x += v1.x; a1.y += v1.y;
        a2.x += v2.x; a2.y += v2.y;
        a3.x += v3.x; a3.y += v3.y;
    }
    for (; r < end; ++r) {
        float2 v = x2[(long)r * 64 + lane];
        a0.x += v.x; a0.y += v.y;
    }
    float2 acc;
    acc.x = (a0.x + a1.x) + (a2.x + a3.x);
    acc.y = (a0.y + a1.y) + (a2.y + a3.y);
    reinterpret_cast<float2*>(out)[(long)seg * 64 + lane] = acc;
}

extern "C" void kernel_launch(void* const* d_in, const int* in_sizes, int n_in,
                              void* d_out, int out_size, void* d_ws, size_t ws_size,
                              hipStream_t stream) {
    const float* x  = (const float*)d_in[0];
    const int* idx  = (const int*)d_in[1];
    float* out      = (float*)d_out;
    int* offsets    = (int*)d_ws;   // (N_SEG + 1) ints = 200 KB, ws is plenty

    seg_offsets_kernel<<<(N_ROWS + 255) / 256, 256, 0, stream>>>(idx, offsets);
    SegmentSum_20272245637565_kernel<<<N_SEG / 4, 256, 0, stream>>>(x, offsets, out);
}

// Round 3
// 67.316 us; speedup vs baseline: 1.5398x; 1.0212x over previous
//
#include <hip/hip_runtime.h>

#define N_ROWS 600000
#define D_FEAT 128
#define N_SEG 50000

// Pass 1: offsets[s] = first row r with idx[r] >= s, for s in [0, N_SEG].
// Sorted index -> each row r where the index changes writes the boundary for
// every segment id in (idx[r-1], idx[r]]. Covers [0, N_SEG] exactly once.
__global__ __launch_bounds__(256) void seg_offsets_kernel(
    const int* __restrict__ idx, int* __restrict__ offsets) {
    int r = blockIdx.x * 256 + threadIdx.x;
    if (r >= N_ROWS) return;
    int cur = idx[r];
    int prev = (r == 0) ? -1 : idx[r - 1];
    for (int s = prev + 1; s <= cur; ++s) offsets[s] = r;
    if (r == N_ROWS - 1)
        for (int s = cur + 1; s <= N_SEG; ++s) offsets[s] = N_ROWS;
}

// Pass 2: one wave per segment, 4 waves per block.
// float4 layout: lane = half*32 + col4. Lanes 0..31 cover one row (32 x 16 B
// = 512 B), the two halves cover rows r and r+1 -> 2 rows (1 KB) per load
// instruction. Unroll x2 -> 4 rows (2 KB) in flight. Cross-half combine via
// __shfl_xor(.,32); half 0 writes the final float4 row.
__global__ __launch_bounds__(256) void SegmentSum_20272245637565_kernel(
    const float* __restrict__ x, const int* __restrict__ offsets,
    float* __restrict__ out) {
    const int wave = threadIdx.x >> 6;
    const int lane = threadIdx.x & 63;
    const int seg  = blockIdx.x * 4 + wave;

    const int start = offsets[seg];
    const int end   = offsets[seg + 1];

    const int half = lane >> 5;   // row parity within a pair
    const int col4 = lane & 31;   // float4 column 0..31

    const float4* __restrict__ x4 = reinterpret_cast<const float4*>(x);

    float4 a0{0.f, 0.f, 0.f, 0.f}, a1{0.f, 0.f, 0.f, 0.f};
    int r = start;
    for (; r + 4 <= end; r += 4) {
        float4 v0 = x4[(long)(r + half) * 32 + col4];
        float4 v1 = x4[(long)(r + 2 + half) * 32 + col4];
        a0.x += v0.x; a0.y += v0.y; a0.z += v0.z; a0.w += v0.w;
        a1.x += v1.x; a1.y += v1.y; a1.z += v1.z; a1.w += v1.w;
    }
    if (r + 2 <= end) {
        float4 v = x4[(long)(r + half) * 32 + col4];
        a0.x += v.x; a0.y += v.y; a0.z += v.z; a0.w += v.w;
        r += 2;
    }
    if (r < end && half == 0) {
        float4 v = x4[(long)r * 32 + col4];
        a0.x += v.x; a0.y += v.y; a0.z += v.z; a0.w += v.w;
    }

    float4 s;
    s.x = a0.x + a1.x; s.y = a0.y + a1.y;
    s.z = a0.z + a1.z; s.w = a0.w + a1.w;

    s.x += __shfl_xor(s.x, 32, 64);
    s.y += __shfl_xor(s.y, 32, 64);
    s.z += __shfl_xor(s.z, 32, 64);
    s.w += __shfl_xor(s.w, 32, 64);

    if (half == 0)
        reinterpret_cast<float4*>(out)[(long)seg * 32 + col4] = s;
}

extern "C" void kernel_launch(void* const* d_in, const int* in_sizes, int n_in,
                              void* d_out, int out_size, void* d_ws, size_t ws_size,
                              hipStream_t stream) {
    const float* x  = (const float*)d_in[0];
    const int* idx  = (const int*)d_in[1];
    float* out      = (float*)d_out;
    int* offsets    = (int*)d_ws;   // (N_SEG + 1) ints = 200 KB

    seg_offsets_kernel<<<(N_ROWS + 255) / 256, 256, 0, stream>>>(idx, offsets);
    SegmentSum_20272245637565_kernel<<<N_SEG / 4, 256, 0, stream>>>(x, offsets, out);
}